// Round 7
// baseline (143.938 us; speedup 1.0000x reference)
//
#include <hip/hip_runtime.h>

#define NUM_EMB 1024
#define WORD_L 24

// One wave (64 lanes) per word. No LDS, no barriers, no atomics:
// pure function of (tok, blockIdx) -> out, so graph replays are
// trivially identical to the first launch.
__global__ __launch_bounds__(256) void bag_hist_nolds(
    const int* __restrict__ tok, float* __restrict__ out, int n_words)
{
    const int tid  = threadIdx.x;
    const int lane = tid & 63;
    const int wid  = blockIdx.x * 4 + (tid >> 6);
    if (wid >= n_words) return;   // wave-uniform branch (wid uniform per wave)

    // Lanes 0..23 load this word's 24 tokens (96 contiguous bytes = one
    // coalesced fetch), then broadcast each to all 64 lanes. srcLane is a
    // compile-time constant -> readlane/broadcast, cheap.
    int t = 0;
    if (lane < WORD_L) t = tok[(size_t)wid * WORD_L + lane];

    int tk[WORD_L];
#pragma unroll
    for (int j = 0; j < WORD_L; ++j) tk[j] = __shfl(t, j);

    // Each lane owns bins v = s*256 + lane*4 + {0..3} for chunk s.
    // Pack the 4 counts as bytes in one u32 (counts <= 24 < 256):
    // d = tok - base; if d < 4, add 1 << (8*d). ~4 VALU per token per
    // 4 bins instead of 8 for separate compare/adds.
#pragma unroll
    for (int s = 0; s < 4; ++s) {
        const int base = s * 256 + lane * 4;
        unsigned packed = 0;
#pragma unroll
        for (int j = 0; j < WORD_L; ++j) {
            unsigned d = (unsigned)(tk[j] - base);
            packed += (d < 4u) ? (1u << (8u * d)) : 0u;
        }
        float4 f;
        f.x = (float)(packed & 0xffu);
        f.y = (float)((packed >> 8) & 0xffu);
        f.z = (float)((packed >> 16) & 0xffu);
        f.w = (float)(packed >> 24);
        if (s == 0 && lane == 0) f.x = 0.0f;  // padding_idx column = bin 0
        *reinterpret_cast<float4*>(&out[(size_t)wid * NUM_EMB + base]) = f;
    }
}

extern "C" void kernel_launch(void* const* d_in, const int* in_sizes, int n_in,
                              void* d_out, int out_size, void* d_ws, size_t ws_size,
                              hipStream_t stream) {
    const int* tok = (const int*)d_in[0];
    float* out = (float*)d_out;
    const int n_words = in_sizes[0] / WORD_L;  // 64*512 = 32768

    const int blocks = (n_words + 3) / 4;      // 4 waves/block, 1 word/wave
    bag_hist_nolds<<<dim3(blocks), dim3(256), 0, stream>>>(tok, out, n_words);
}

// Round 8
// 133.366 us; speedup vs baseline: 1.0793x; 1.0793x over previous
//
#include <hip/hip_runtime.h>

#define NUM_EMB 1024
#define WORD_L 24

// One wave per word; stateless (no LDS/barriers/atomics) -> replay-invariant.
// Each lane owns bins {s*256 + lane*4 + 0..3} for chunk s=0..3, counting via
// packed byte counters (counts <= 24 < 256).
__global__ __launch_bounds__(256) void bag_hist_nolds2(
    const int* __restrict__ tok, float* __restrict__ out, int n_words)
{
    const int tid  = threadIdx.x;
    const int lane = tid & 63;
    // readfirstlane: provably wave-uniform word id -> token loads can
    // scalarize to s_load (tokens are wave-uniform), tk[] lives in SGPRs.
    const int wid = __builtin_amdgcn_readfirstlane(blockIdx.x * 4 + (tid >> 6));
    if (wid >= n_words) return;

    const int* wtok = tok + (size_t)wid * WORD_L;
    int tk[WORD_L];
#pragma unroll
    for (int j = 0; j < WORD_L; ++j) tk[j] = wtok[j];

    const unsigned base4 = (unsigned)(lane << 2);
    unsigned p0 = 0, p1 = 0, p2 = 0, p3 = 0;
#pragma unroll
    for (int j = 0; j < WORD_L; ++j) {
        // e = tk - lane*4 (unsigned). Hit for chunk s iff e in [256s, 256s+4),
        // i.e. e>>2 == 64s. Negative tk-base4 wraps to huge e2: no false hit.
        unsigned e   = (unsigned)tk[j] - base4;
        unsigned inc = 1u << ((e & 3u) << 3);  // byte slot within the u32
        unsigned e2  = e >> 2;
        p0 += (e2 == 0u)   ? inc : 0u;
        p1 += (e2 == 64u)  ? inc : 0u;
        p2 += (e2 == 128u) ? inc : 0u;
        p3 += (e2 == 192u) ? inc : 0u;
    }

    float* wout = out + (size_t)wid * NUM_EMB + base4;
#pragma unroll
    for (int s = 0; s < 4; ++s) {
        unsigned p = (s == 0) ? p0 : (s == 1) ? p1 : (s == 2) ? p2 : p3;
        float4 f;
        f.x = (float)(p & 0xffu);
        f.y = (float)((p >> 8) & 0xffu);
        f.z = (float)((p >> 16) & 0xffu);
        f.w = (float)(p >> 24);
        if (s == 0 && lane == 0) f.x = 0.0f;  // padding_idx column (bin 0)
        *reinterpret_cast<float4*>(&wout[s * 256]) = f;
    }
}

extern "C" void kernel_launch(void* const* d_in, const int* in_sizes, int n_in,
                              void* d_out, int out_size, void* d_ws, size_t ws_size,
                              hipStream_t stream) {
    const int* tok = (const int*)d_in[0];
    float* out = (float*)d_out;
    const int n_words = in_sizes[0] / WORD_L;  // 64*512 = 32768

    const int blocks = (n_words + 3) / 4;      // 4 waves/block, 1 word/wave
    bag_hist_nolds2<<<dim3(blocks), dim3(256), 0, stream>>>(tok, out, n_words);
}